// Round 1
// baseline (32734.961 us; speedup 1.0000x reference)
//
#include <hip/hip_runtime.h>
#include <math.h>

#define E 512
#define S_MAX 32
#define BATCH 32
#define HEADS 8
#define DH 64
#define HID 2048
#define VOCAB 30000

// ---------------- positional encoding ----------------
__global__ void pe_kernel(float* __restrict__ PEp) {
    int s = blockIdx.x;
    for (int e = threadIdx.x; e < E; e += 256) {
        float expo = (float)(e & ~1) / (float)E;
        float den = powf(10000.0f, expo);
        float ang = (float)s / den;
        PEp[s * E + e] = (e & 1) ? cosf(ang) : sinf(ang);
    }
}

// ---------------- x = Ybuf + pe (compact rows 0..Seff-1 per batch) ----------------
__global__ void build_x_kernel(float* __restrict__ X, const float* __restrict__ Ybuf,
                               const float* __restrict__ PEp, int Seff) {
    long idx = (long)blockIdx.x * 256 + threadIdx.x;
    long total = (long)BATCH * Seff * E;
    if (idx >= total) return;
    int e = (int)(idx & (E - 1));
    long m = idx >> 9;                 // /E
    int b = (int)(m / Seff);
    int s = (int)(m - (long)b * Seff);
    X[idx] = Ybuf[((long)b * S_MAX + s) * E + e] + PEp[s * E + e];
}

// ---------------- generic tiled f32 GEMM: C = A(MxK) * W(KxN) + bias, opt ReLU ----------------
// grid.z slices: W += z*wz, C += z*cz, bias += z*bz
template <int RELU>
__global__ __launch_bounds__(256) void gemm_kernel(const float* __restrict__ A,
                                                   const float* __restrict__ W,
                                                   const float* __restrict__ bias,
                                                   float* __restrict__ C,
                                                   int M, int N, int K,
                                                   long wz, long cz, long bz) {
    int z = blockIdx.z;
    W += (long)z * wz;
    C += (long)z * cz;
    bias += (long)z * bz;
    int n0 = blockIdx.x * 64;
    int m0 = blockIdx.y * 64;
    int tid = threadIdx.x;
    int tx = tid & 15, ty = tid >> 4;

    __shared__ float As[16][68];   // [k][m], padded (bank-conflict)
    __shared__ float Ws[16][64];   // [k][n]

    float acc[4][4];
#pragma unroll
    for (int i = 0; i < 4; i++)
#pragma unroll
        for (int j = 0; j < 4; j++) acc[i][j] = 0.f;

    for (int k0 = 0; k0 < K; k0 += 16) {
#pragma unroll
        for (int l = 0; l < 4; l++) {
            int idx = tid + l * 256;
            int m = idx >> 4, k = idx & 15;
            int mm = m0 + m;
            if (mm >= M) mm = M - 1;           // clamp; extra rows never stored
            As[k][m] = A[(long)mm * K + k0 + k];
        }
#pragma unroll
        for (int l = 0; l < 4; l++) {
            int idx = tid + l * 256;
            int k = idx >> 6, n = idx & 63;
            Ws[k][n] = W[(long)(k0 + k) * N + n0 + n];
        }
        __syncthreads();
#pragma unroll
        for (int k = 0; k < 16; k++) {
            float a0 = As[k][ty * 4 + 0], a1 = As[k][ty * 4 + 1];
            float a2 = As[k][ty * 4 + 2], a3 = As[k][ty * 4 + 3];
            float w0 = Ws[k][tx * 4 + 0], w1 = Ws[k][tx * 4 + 1];
            float w2 = Ws[k][tx * 4 + 2], w3 = Ws[k][tx * 4 + 3];
            acc[0][0] += a0 * w0; acc[0][1] += a0 * w1; acc[0][2] += a0 * w2; acc[0][3] += a0 * w3;
            acc[1][0] += a1 * w0; acc[1][1] += a1 * w1; acc[1][2] += a1 * w2; acc[1][3] += a1 * w3;
            acc[2][0] += a2 * w0; acc[2][1] += a2 * w1; acc[2][2] += a2 * w2; acc[2][3] += a2 * w3;
            acc[3][0] += a3 * w0; acc[3][1] += a3 * w1; acc[3][2] += a3 * w2; acc[3][3] += a3 * w3;
        }
        __syncthreads();
    }
#pragma unroll
    for (int i = 0; i < 4; i++) {
        int m = m0 + ty * 4 + i;
        if (m < M) {
#pragma unroll
            for (int j = 0; j < 4; j++) {
                int n = n0 + tx * 4 + j;
                float v = acc[i][j] + bias[n];
                if (RELU) v = fmaxf(v, 0.f);
                C[(long)m * N + n] = v;
            }
        }
    }
}

// ---------------- attention: one (q-row, head, batch) per 64-thread block ----------------
// Q compact (BATCH*Seff, E); K/V rows at base + b*kvBatchStride + k*E + h*DH
__global__ __launch_bounds__(64) void attn_kernel(const float* __restrict__ Q,
                                                  const float* __restrict__ Kp,
                                                  const float* __restrict__ Vp,
                                                  float* __restrict__ O,
                                                  int Seff, int kvBatchStride) {
    int s = blockIdx.x, h = blockIdx.y, b = blockIdx.z;
    int lane = threadIdx.x;
    __shared__ float qs[DH];
    qs[lane] = Q[((long)(b * Seff + s)) * E + h * DH + lane];
    __syncthreads();

    float sc = -INFINITY;
    if (lane < Seff) {
        const float4* k4 = (const float4*)(Kp + (long)b * kvBatchStride + (long)lane * E + h * DH);
        const float4* q4 = (const float4*)qs;
        float acc = 0.f;
#pragma unroll
        for (int d = 0; d < DH / 4; d++) {
            float4 kv = k4[d];
            float4 qv = q4[d];
            acc += qv.x * kv.x;
            acc += qv.y * kv.y;
            acc += qv.z * kv.z;
            acc += qv.w * kv.w;
        }
        sc = acc * 0.125f;   // /sqrt(64)
    }
    float m = sc;
#pragma unroll
    for (int off = 32; off; off >>= 1) m = fmaxf(m, __shfl_xor(m, off));
    float p = (lane < Seff) ? expf(sc - m) : 0.f;
    float sum = p;
#pragma unroll
    for (int off = 32; off; off >>= 1) sum += __shfl_xor(sum, off);
    p = p / sum;

    float acc = 0.f;
    const float* vbase = Vp + (long)b * kvBatchStride + h * DH + lane;
    for (int k = 0; k < Seff; k++) {
        float pk = __shfl(p, k);
        acc = fmaf(pk, vbase[(long)k * E], acc);
    }
    O[((long)(b * Seff + s)) * E + h * DH + lane] = acc;
}

// ---------------- x = LN(x + delta) row-wise ----------------
__global__ __launch_bounds__(64) void resid_ln_kernel(float* __restrict__ X,
                                                      const float* __restrict__ Dlt,
                                                      const float* __restrict__ g,
                                                      const float* __restrict__ bb) {
    long row = blockIdx.x;
    int lane = threadIdx.x;
    float* xr = X + row * E;
    const float* dr = Dlt + row * E;
    float v[8];
    float s = 0.f;
#pragma unroll
    for (int i = 0; i < 8; i++) {
        int e = lane + i * 64;
        v[i] = xr[e] + dr[e];
        s += v[i];
    }
#pragma unroll
    for (int off = 32; off; off >>= 1) s += __shfl_xor(s, off);
    float mean = s * (1.0f / E);
    float sq = 0.f;
#pragma unroll
    for (int i = 0; i < 8; i++) {
        float d = v[i] - mean;
        sq += d * d;
    }
#pragma unroll
    for (int off = 32; off; off >>= 1) sq += __shfl_xor(sq, off);
    float var = sq * (1.0f / E);
    float r = 1.0f / sqrtf(var + 1e-5f);
#pragma unroll
    for (int i = 0; i < 8; i++) {
        int e = lane + i * 64;
        xr[e] = (v[i] - mean) * r * g[e] + bb[e];
    }
}

// ---------------- logits = tok(B x E) @ soft_W(E x V) + soft_b ----------------
// block: 64 n-lanes x 4 k-quarters; tok rows read as wave-uniform scalar loads
__global__ __launch_bounds__(256) void logits_kernel(const float* __restrict__ X,
                                                     const float* __restrict__ SW,
                                                     const float* __restrict__ sb,
                                                     float* __restrict__ Lg,
                                                     int Seff, int t) {
    int nl = threadIdx.x & 63;
    int kq = threadIdx.x >> 6;
    int n = blockIdx.x * 64 + nl;
    bool nok = n < VOCAB;
    float acc[BATCH];
#pragma unroll
    for (int b = 0; b < BATCH; b++) acc[b] = 0.f;
    if (nok) {
        int k0 = kq * 128;
        for (int k = k0; k < k0 + 128; k++) {
            float wv = SW[(long)k * VOCAB + n];
#pragma unroll
            for (int b = 0; b < BATCH; b++) {
                acc[b] = fmaf(X[((long)(b * Seff + t)) * E + k], wv, acc[b]);
            }
        }
    }
    __shared__ float red[4][64];
    for (int b = 0; b < BATCH; b++) {
        red[kq][nl] = acc[b];
        __syncthreads();
        if (kq == 0 && nok) {
            float sum = red[0][nl] + red[1][nl] + red[2][nl] + red[3][nl] + sb[n];
            Lg[(long)b * VOCAB + n] = sum;
        }
        __syncthreads();
    }
}

// ---------------- softmax -> out[:,t,:], argmax -> Ybuf[:,t,:] = w2v[idx] ----------------
__global__ __launch_bounds__(256) void softmax_out_kernel(const float* __restrict__ Lg,
                                                          float* __restrict__ Out,
                                                          const float* __restrict__ w2v,
                                                          float* __restrict__ Ybuf, int t) {
    int b = blockIdx.x;
    int tid = threadIdx.x;
    const float* lb = Lg + (long)b * VOCAB;
    __shared__ float red[256];

    float m = -INFINITY;
    for (int n = tid; n < VOCAB; n += 256) m = fmaxf(m, lb[n]);
    red[tid] = m;
    __syncthreads();
    for (int off = 128; off; off >>= 1) {
        if (tid < off) red[tid] = fmaxf(red[tid], red[tid + off]);
        __syncthreads();
    }
    m = red[0];
    __syncthreads();

    float s = 0.f;
    for (int n = tid; n < VOCAB; n += 256) s += expf(lb[n] - m);
    red[tid] = s;
    __syncthreads();
    for (int off = 128; off; off >>= 1) {
        if (tid < off) red[tid] += red[tid + off];
        __syncthreads();
    }
    s = red[0];
    __syncthreads();

    float bestv = -1.0f;
    int besti = VOCAB;
    float* ob = Out + ((long)b * S_MAX + t) * VOCAB;
    for (int n = tid; n < VOCAB; n += 256) {
        float p = expf(lb[n] - m) / s;
        ob[n] = p;
        if (p > bestv) { bestv = p; besti = n; }   // increasing n: strict > keeps first
    }
    __shared__ float rv[256];
    __shared__ int ri[256];
    rv[tid] = bestv;
    ri[tid] = besti;
    __syncthreads();
    for (int off = 128; off; off >>= 1) {
        if (tid < off) {
            float v2 = rv[tid + off];
            int i2 = ri[tid + off];
            if (v2 > rv[tid] || (v2 == rv[tid] && i2 < ri[tid])) { rv[tid] = v2; ri[tid] = i2; }
        }
        __syncthreads();
    }
    int idx = ri[0];
    float* yb = Ybuf + ((long)b * S_MAX + t) * E;
    for (int e = tid; e < E; e += 256) yb[e] = w2v[(long)idx * E + e];
}

// =====================================================================
extern "C" void kernel_launch(void* const* d_in, const int* in_sizes, int n_in,
                              void* d_out, int out_size, void* d_ws, size_t ws_size,
                              hipStream_t stream) {
    const float* noise    = (const float*)d_in[0];
    const float* seeds    = (const float*)d_in[1];
    const float* inemb_W  = (const float*)d_in[2];
    const float* inemb_b  = (const float*)d_in[3];
    const float* g_attn_W = (const float*)d_in[4];
    const float* g_attn_b = (const float*)d_in[5];
    const float* g_cross_W= (const float*)d_in[6];
    const float* g_cross_b= (const float*)d_in[7];
    const float* g_ffn_W1 = (const float*)d_in[8];
    const float* g_ffn_b1 = (const float*)d_in[9];
    const float* g_ffn_W2 = (const float*)d_in[10];
    const float* g_ffn_b2 = (const float*)d_in[11];
    const float* g_ln_g   = (const float*)d_in[12];
    const float* g_ln_b   = (const float*)d_in[13];
    const float* o_attn_W = (const float*)d_in[14];
    const float* o_attn_b = (const float*)d_in[15];
    const float* o_ffn_W1 = (const float*)d_in[16];
    const float* o_ffn_b1 = (const float*)d_in[17];
    const float* o_ffn_W2 = (const float*)d_in[18];
    const float* o_ffn_b2 = (const float*)d_in[19];
    const float* o_ln_g   = (const float*)d_in[20];
    const float* o_ln_b   = (const float*)d_in[21];
    const float* w2v      = (const float*)d_in[22];
    const float* soft_W   = (const float*)d_in[23];
    const float* soft_b   = (const float*)d_in[24];
    float* out = (float*)d_out;
    float* ws = (float*)d_ws;

    const long EE  = (long)E * E;                 // 262144
    const long BSE = (long)BATCH * S_MAX * E;     // 524288

    float* PE   = ws;
    float* WEMB = PE + 16384;
    float* KWVW = WEMB + BSE;                     // [blk][K|V] : 4*BSE
    float* YBUF = KWVW + 4 * BSE;
    float* X    = YBUF + BSE;
    float* QKV  = X + BSE;                        // 3*BSE
    float* AOUT = QKV + 3 * BSE;
    float* TMP  = AOUT + BSE;
    float* HB   = TMP + BSE;                      // BATCH*S_MAX*HID
    float* LG   = HB + (long)BATCH * S_MAX * HID; // BATCH*VOCAB

    auto GEMM = [&](const float* A, const float* W, const float* bias, float* C,
                    int M, int N, int K, int Z, long wz, long cz, long bz, bool relu) {
        dim3 g(N / 64, (M + 63) / 64, Z);
        if (relu)
            gemm_kernel<1><<<g, dim3(256), 0, stream>>>(A, W, bias, C, M, N, K, wz, cz, bz);
        else
            gemm_kernel<0><<<g, dim3(256), 0, stream>>>(A, W, bias, C, M, N, K, wz, cz, bz);
    };

    // ---- precompute ----
    pe_kernel<<<dim3(S_MAX), dim3(256), 0, stream>>>(PE);
    hipMemcpyAsync(YBUF, seeds, BSE * sizeof(float), hipMemcpyDeviceToDevice, stream);

    GEMM(noise, inemb_W, inemb_b, QKV, BATCH * S_MAX, E, E, 1, 0, 0, 0, false);
    GEMM(QKV, inemb_W + EE, inemb_b + E, WEMB, BATCH * S_MAX, E, E, 1, 0, 0, 0, false);

    for (int i = 0; i < 2; i++) {   // cross K/V from constant w
        GEMM(WEMB, g_cross_W + i * 4 * EE + EE, g_cross_b + i * 4 * E + E,
             KWVW + i * 2 * BSE, BATCH * S_MAX, E, E, 2, EE, BSE, E, false);
    }

    // ---- autoregressive scan ----
    for (int t = 0; t < S_MAX; t++) {
        int Seff = t + 1;
        int Mrows = BATCH * Seff;
        long ME = (long)Mrows * E;
        int total = Mrows * E;

        build_x_kernel<<<dim3((total + 255) / 256), dim3(256), 0, stream>>>(X, YBUF, PE, Seff);

        for (int i = 0; i < 2; i++) {
            const float* AW = g_attn_W + i * 4 * EE;
            const float* Ab = g_attn_b + i * 4 * E;
            // self-attn
            GEMM(X, AW, Ab, QKV, Mrows, E, E, 3, EE, ME, E, false);
            attn_kernel<<<dim3(Seff, HEADS, BATCH), dim3(64), 0, stream>>>(
                QKV, QKV + ME, QKV + 2 * ME, AOUT, Seff, Seff * E);
            GEMM(AOUT, AW + 3 * EE, Ab + 3 * E, TMP, Mrows, E, E, 1, 0, 0, 0, false);
            resid_ln_kernel<<<dim3(Mrows), dim3(64), 0, stream>>>(
                X, TMP, g_ln_g + (i * 3 + 0) * E, g_ln_b + (i * 3 + 0) * E);
            // cross-attn (K/V precomputed, full-S stride)
            const float* CW = g_cross_W + i * 4 * EE;
            const float* Cb = g_cross_b + i * 4 * E;
            GEMM(X, CW, Cb, QKV, Mrows, E, E, 1, 0, 0, 0, false);
            attn_kernel<<<dim3(Seff, HEADS, BATCH), dim3(64), 0, stream>>>(
                QKV, KWVW + i * 2 * BSE, KWVW + i * 2 * BSE + BSE, AOUT, Seff, S_MAX * E);
            GEMM(AOUT, CW + 3 * EE, Cb + 3 * E, TMP, Mrows, E, E, 1, 0, 0, 0, false);
            resid_ln_kernel<<<dim3(Mrows), dim3(64), 0, stream>>>(
                X, TMP, g_ln_g + (i * 3 + 1) * E, g_ln_b + (i * 3 + 1) * E);
            // FFN
            GEMM(X, g_ffn_W1 + i * (long)E * HID, g_ffn_b1 + i * HID, HB, Mrows, HID, E,
                 1, 0, 0, 0, true);
            GEMM(HB, g_ffn_W2 + i * (long)HID * E, g_ffn_b2 + i * E, TMP, Mrows, E, HID,
                 1, 0, 0, 0, false);
            resid_ln_kernel<<<dim3(Mrows), dim3(64), 0, stream>>>(
                X, TMP, g_ln_g + (i * 3 + 2) * E, g_ln_b + (i * 3 + 2) * E);
        }
        // o block
        GEMM(X, o_attn_W, o_attn_b, QKV, Mrows, E, E, 3, EE, ME, E, false);
        attn_kernel<<<dim3(Seff, HEADS, BATCH), dim3(64), 0, stream>>>(
            QKV, QKV + ME, QKV + 2 * ME, AOUT, Seff, Seff * E);
        GEMM(AOUT, o_attn_W + 3 * EE, o_attn_b + 3 * E, TMP, Mrows, E, E, 1, 0, 0, 0, false);
        resid_ln_kernel<<<dim3(Mrows), dim3(64), 0, stream>>>(X, TMP, o_ln_g, o_ln_b);
        GEMM(X, o_ffn_W1, o_ffn_b1, HB, Mrows, HID, E, 1, 0, 0, 0, true);
        GEMM(HB, o_ffn_W2, o_ffn_b2, TMP, Mrows, E, HID, 1, 0, 0, 0, false);
        resid_ln_kernel<<<dim3(Mrows), dim3(64), 0, stream>>>(X, TMP, o_ln_g + E, o_ln_b + E);

        // logits -> softmax -> out + token feedback
        logits_kernel<<<dim3((VOCAB + 63) / 64), dim3(256), 0, stream>>>(X, soft_W, soft_b, LG, Seff, t);
        softmax_out_kernel<<<dim3(BATCH), dim3(256), 0, stream>>>(LG, out, w2v, YBUF, t);
    }
}